// Round 7
// baseline (1195.762 us; speedup 1.0000x reference)
//
#include <hip/hip_runtime.h>
#include <hip/hip_bf16.h>

#define T_TOK 4096
#define DDIM  1024
#define HDIM  2048
#define NEXP  8

typedef __attribute__((ext_vector_type(4))) float f32x4;
typedef __attribute__((ext_vector_type(8))) short s16x8;
typedef __hip_bfloat16 bf16;

typedef const void __attribute__((address_space(1))) gvoid;
typedef void __attribute__((address_space(3))) svoid;

__device__ __forceinline__ void gload16(const void* g, void* l) {
    // async global->LDS, 16B/lane; LDS dest = wave-uniform base, HW adds lane*16
    __builtin_amdgcn_global_load_lds((gvoid*)g, (svoid*)l, 16, 0, 0);
}

// Swizzled LDS layout for BK=32 tiles (verified 0 bank conflicts in R6):
// real rows paired into 64-elem LDS rows; 16B chunk XOR'd with (ldsrow&7).
// read addr for (realrow rr, k-offset kq in {0,8,16,24}): ldsrow=rr>>1,
// chunk=((rr&1)<<2)+(kq>>3), elem_off = ldsrow*64 + (chunk ^ (ldsrow&7))*8.
__device__ __forceinline__ int frag_off(int rr, int kq) {
    int lr = rr >> 1;
    int ch = ((rr & 1) << 2) + (kq >> 3);
    return lr * 64 + (ch ^ (lr & 7)) * 8;
}

// ---------------- router (fp64 acc, top-2 softmax) + fused x->bf16 cast ----------------
__global__ void router_cast_kernel(const float* __restrict__ x, const float* __restrict__ rw,
                                   int* __restrict__ r_e, float* __restrict__ r_w,
                                   bf16* __restrict__ xb) {
    int wave = threadIdx.x >> 6, lane = threadIdx.x & 63;
    int t = blockIdx.x * 4 + wave;
    const float* xr = x + (size_t)t * DDIM;
    bf16* xbr = xb + (size_t)t * DDIM;
    double acc[NEXP];
#pragma unroll
    for (int e = 0; e < NEXP; ++e) acc[e] = 0.0;
#pragma unroll
    for (int c = 0; c < 4; ++c) {
        int d = c * 256 + lane * 4;
        float4 v = *reinterpret_cast<const float4*>(xr + d);
        union { ushort4 u; bf16 h[4]; } o;
        o.h[0] = __float2bfloat16(v.x);
        o.h[1] = __float2bfloat16(v.y);
        o.h[2] = __float2bfloat16(v.z);
        o.h[3] = __float2bfloat16(v.w);
        *reinterpret_cast<ushort4*>(xbr + d) = o.u;
        const float* rw0 = rw + (size_t)d * NEXP;
#pragma unroll
        for (int j = 0; j < 4; ++j) {
            float xv = (&v.x)[j];
            const float* rwr = rw0 + j * NEXP;
#pragma unroll
            for (int e = 0; e < NEXP; ++e) acc[e] += (double)xv * (double)rwr[e];
        }
    }
#pragma unroll
    for (int e = 0; e < NEXP; ++e) {
#pragma unroll
        for (int off = 32; off > 0; off >>= 1) acc[e] += __shfl_down(acc[e], off);
    }
    if (lane == 0) {
        int i0 = 0; double v0 = acc[0];
#pragma unroll
        for (int e = 1; e < NEXP; ++e) if (acc[e] > v0) { v0 = acc[e]; i0 = e; }
        int i1 = -1; double v1 = -1e300;
#pragma unroll
        for (int e = 0; e < NEXP; ++e) { if (e == i0) continue; if (acc[e] > v1) { v1 = acc[e]; i1 = e; } }
        float w0 = 1.0f / (1.0f + expf((float)(v1 - v0)));
        float w1 = 1.0f - w0;
        r_e[2*t]   = i0; r_e[2*t+1] = i1;
        r_w[2*t]   = w0; r_w[2*t+1] = w1;
    }
}

// ---------------- fused binning: count + scan + fill in one block ----------------
__global__ void binning_kernel(const int* __restrict__ r_e, const float* __restrict__ r_w,
                               int* __restrict__ offs, int* __restrict__ list,
                               float* __restrict__ slot_w) {
    __shared__ int scnt[NEXP], scur[NEXP], soff[NEXP + 1];
    int tid = threadIdx.x;
    if (tid < NEXP) { scnt[tid] = 0; scur[tid] = 0; }
    __syncthreads();
    for (int i = tid; i < 2 * T_TOK; i += 512) atomicAdd(&scnt[r_e[i]], 1);
    __syncthreads();
    if (tid == 0) {
        int s = 0;
        for (int e = 0; e < NEXP; ++e) { soff[e] = s; s += scnt[e]; }
        soff[NEXP] = s;
    }
    __syncthreads();
    if (tid < NEXP + 1) offs[tid] = soff[tid];
    for (int i = tid; i < 2 * T_TOK; i += 512) {
        int e = r_e[i];
        int pos = atomicAdd(&scur[e], 1);
        int slot = soff[e] + pos;
        list[slot] = i >> 1;
        slot_w[slot] = r_w[i];
    }
}

// ---------------- transpose + fp32->bf16 cast (vectorized, generalized) ----------------
__global__ void transpose_cast_kernel(const float* __restrict__ in, bf16* __restrict__ out,
                                      int R, int C, int rmul, int roff, size_t outE) {
    __shared__ bf16 tile[64][68];
    const float* inp = in + (size_t)blockIdx.z * R * C;
    bf16* outp = out + (size_t)blockIdx.z * outE;
    int r0 = blockIdx.x * 64, c0 = blockIdx.y * 64;
    int tid = threadIdx.x;
#pragma unroll
    for (int i = 0; i < 4; ++i) {
        int idx = i * 256 + tid;
        int r = idx >> 4, c4 = (idx & 15) * 4;
        float4 v = *reinterpret_cast<const float4*>(inp + (size_t)(r0 + r) * C + c0 + c4);
        tile[r][c4 + 0] = __float2bfloat16(v.x);
        tile[r][c4 + 1] = __float2bfloat16(v.y);
        tile[r][c4 + 2] = __float2bfloat16(v.z);
        tile[r][c4 + 3] = __float2bfloat16(v.w);
    }
    __syncthreads();
#pragma unroll
    for (int i = 0; i < 4; ++i) {
        int idx = i * 256 + tid;
        int c = idx >> 4, r4 = (idx & 15) * 4;
        union { ushort4 u; bf16 h[4]; } w;
        w.h[0] = tile[r4 + 0][c];
        w.h[1] = tile[r4 + 1][c];
        w.h[2] = tile[r4 + 2][c];
        w.h[3] = tile[r4 + 3][c];
        *reinterpret_cast<ushort4*>(outp + ((size_t)(c0 + c) * rmul + roff) * R + r0 + r4) = w.u;
    }
}

// ======== pass 1: gate+up as ONE GEMM over interleaved wguT [2H][D] ========
// 256x256 tile, BK=32, 2 LDS bufs (64KB -> 2 blocks/CU), 8 waves (2M x 4N,
// wave-out 128x64 -> 0.375 ds_read/MFMA). R4's proven cadence: counted vmcnt(4),
// never drained in steady state; stage(t+2) right after the buffer-free barrier.
__global__ __launch_bounds__(512, 4)
void gateup_kernel(const bf16* __restrict__ xb, const bf16* __restrict__ wguT,
                   const int* __restrict__ offs, const int* __restrict__ list,
                   bf16* __restrict__ hbuf) {
    int e = blockIdx.z;
    int base = offs[e];
    int ne = offs[e + 1] - base;
    int m0 = blockIdx.y * 256;
    if (m0 >= ne) return;
    int n0 = blockIdx.x * 256;   // in 2H=4096 interleaved space

    __shared__ bf16 As[2][8192];   // 256 rows x 32 k, swizzled pairs
    __shared__ bf16 Bs[2][8192];

    int tid = threadIdx.x, lane = tid & 63, wid = tid >> 6;

    const bf16* bbase = wguT + (size_t)e * (2 * HDIM) * DDIM + (size_t)n0 * DDIM;

    // staging sources (inverse-swizzled global addresses; LDS dest linear)
    const bf16* aS[2]; const bf16* bS[2];
#pragma unroll
    for (int l = 0; l < 2; ++l) {
        int ldsrow = l * 64 + (tid >> 3);
        int oc = (tid & 7) ^ (ldsrow & 7);
        int half = oc >> 2, ko = (oc & 3) * 8;
        int realrow = 2 * ldsrow + half;
        int r = m0 + realrow; if (r > ne - 1) r = ne - 1;   // clamp: read-only, never stored
        aS[l] = xb + (size_t)list[base + r] * DDIM + ko;
        bS[l] = bbase + (size_t)realrow * DDIM + ko;
    }
    int dstoff = wid * 512;   // elems; + l*4096

    int rl = lane & 15, kq = 8 * (lane >> 4);
    int wrow = (wid >> 2) * 128;     // 2 M waves
    int wcol = (wid & 3) * 64;       // 4 N waves
    int offA[8], offB[4];
#pragma unroll
    for (int mi = 0; mi < 8; ++mi) offA[mi] = frag_off(wrow + mi * 16 + rl, kq);
#pragma unroll
    for (int ni = 0; ni < 4; ++ni) offB[ni] = frag_off(wcol + ni * 16 + rl, kq);

    f32x4 zero4 = {0.f, 0.f, 0.f, 0.f};
    f32x4 acc[8][4];
#pragma unroll
    for (int mi = 0; mi < 8; ++mi)
#pragma unroll
        for (int ni = 0; ni < 4; ++ni) acc[mi][ni] = zero4;

    const int nk = DDIM / 32;   // 32

#define GU_STAGE(tt, buf)                                             \
    {                                                                 \
        int k0 = (tt) * 32;                                           \
        gload16(aS[0] + k0, &As[buf][dstoff]);                        \
        gload16(aS[1] + k0, &As[buf][4096 + dstoff]);                 \
        gload16(bS[0] + k0, &Bs[buf][dstoff]);                        \
        gload16(bS[1] + k0, &Bs[buf][4096 + dstoff]);                 \
    }

    // prologue: stage tiles 0,1; wait tile0 (tile1's 4 loads stay in flight)
    GU_STAGE(0, 0);
    GU_STAGE(1, 1);
    asm volatile("s_waitcnt vmcnt(4)" ::: "memory");
    __builtin_amdgcn_s_barrier();

    for (int t = 0; t < nk; ++t) {
        const bf16* Ab = As[t & 1];
        const bf16* Bb = Bs[t & 1];
        s16x8 a[8], b[4];
#pragma unroll
        for (int mi = 0; mi < 8; ++mi) a[mi] = *reinterpret_cast<const s16x8*>(Ab + offA[mi]);
#pragma unroll
        for (int ni = 0; ni < 4; ++ni) b[ni] = *reinterpret_cast<const s16x8*>(Bb + offB[ni]);
        __builtin_amdgcn_s_setprio(1);
#pragma unroll
        for (int mi = 0; mi < 8; ++mi)
#pragma unroll
            for (int ni = 0; ni < 4; ++ni)
                acc[mi][ni] = __builtin_amdgcn_mfma_f32_16x16x32_bf16(a[mi], b[ni], acc[mi][ni], 0, 0, 0);
        __builtin_amdgcn_s_setprio(0);
        __builtin_amdgcn_sched_barrier(0);
        __builtin_amdgcn_s_barrier();                 // buf[t&1] free
        if (t + 2 < nk) GU_STAGE(t + 2, t & 1);       // in flight: t+1(4) + t+2(4)
        if (t + 1 < nk) {
            if (t + 2 < nk) asm volatile("s_waitcnt vmcnt(4)" ::: "memory");
            else            asm volatile("s_waitcnt vmcnt(0)" ::: "memory");
            __builtin_amdgcn_s_barrier();             // tile t+1 fully in LDS
        }
    }
#undef GU_STAGE

    // epilogue: even col = gate, odd col = up; pair via shfl_xor(1), even lanes store.
    int rbase = (lane >> 4) * 4, cbase = lane & 15;
    bool evenlane = (lane & 1) == 0;
#pragma unroll
    for (int mi = 0; mi < 8; ++mi) {
#pragma unroll
        for (int ni = 0; ni < 4; ++ni) {
#pragma unroll
            for (int r = 0; r < 4; ++r) {
                float own = acc[mi][ni][r];
                float oth = __shfl_xor(own, 1);
                int row = m0 + wrow + mi * 16 + rbase + r;
                if (evenlane && row < ne) {
                    float g = own, u = oth;
                    float h = (g / (1.0f + expf(-g))) * u;
                    int hcol = (n0 + wcol + ni * 16 + cbase) >> 1;
                    hbuf[(size_t)(base + row) * HDIM + hcol] = __float2bfloat16(h);
                }
            }
        }
    }
}

// ======== pass 2: down GEMM 128x256, BK=32, 2 bufs (48KB -> 3 blocks/CU) ========
// counted vmcnt(3); fused combine via deterministic atomicAdd into zeroed y
// (exactly 2 commutative fp32 adds per element).
__global__ __launch_bounds__(512, 4)
void down_kernel(const bf16* __restrict__ hbuf, const bf16* __restrict__ wdT,
                 const int* __restrict__ offs, const int* __restrict__ list,
                 const float* __restrict__ slot_w, float* __restrict__ y) {
    int e = blockIdx.z;
    int base = offs[e];
    int ne = offs[e + 1] - base;
    int m0 = blockIdx.y * 128;
    if (m0 >= ne) return;
    int n0 = blockIdx.x * 256;   // d-tile

    __shared__ bf16 As[2][4096];   // 128 rows x 32 k
    __shared__ bf16 Bs[2][8192];   // 256 rows x 32 k

    int tid = threadIdx.x, lane = tid & 63, wid = tid >> 6;

    const bf16* bbase = wdT + (size_t)e * DDIM * HDIM + (size_t)n0 * HDIM;

    const bf16* aS; const bf16* bS[2];
    {
        int ldsrow = tid >> 3;
        int oc = (tid & 7) ^ (ldsrow & 7);
        int half = oc >> 2, ko = (oc & 3) * 8;
        int realrow = 2 * ldsrow + half;
        int r = m0 + realrow; if (r > ne - 1) r = ne - 1;
        aS = hbuf + (size_t)(base + r) * HDIM + ko;
    }
#pragma unroll
    for (int l = 0; l < 2; ++l) {
        int ldsrow = l * 64 + (tid >> 3);
        int oc = (tid & 7) ^ (ldsrow & 7);
        int half = oc >> 2, ko = (oc & 3) * 8;
        int realrow = 2 * ldsrow + half;
        bS[l] = bbase + (size_t)realrow * HDIM + ko;
    }
    int dstoff = wid * 512;

    int rl = lane & 15, kq = 8 * (lane >> 4);
    int wrow = (wid >> 2) * 64;
    int wcol = (wid & 3) * 64;
    int offA[4], offB[4];
#pragma unroll
    for (int mi = 0; mi < 4; ++mi) offA[mi] = frag_off(wrow + mi * 16 + rl, kq);
#pragma unroll
    for (int ni = 0; ni < 4; ++ni) offB[ni] = frag_off(wcol + ni * 16 + rl, kq);

    f32x4 zero4 = {0.f, 0.f, 0.f, 0.f};
    f32x4 acc[4][4];
#pragma unroll
    for (int mi = 0; mi < 4; ++mi)
#pragma unroll
        for (int ni = 0; ni < 4; ++ni) acc[mi][ni] = zero4;

    const int nk = HDIM / 32;   // 64

#define DN_STAGE(tt, buf)                                             \
    {                                                                 \
        int k0 = (tt) * 32;                                           \
        gload16(aS + k0, &As[buf][dstoff]);                           \
        gload16(bS[0] + k0, &Bs[buf][dstoff]);                        \
        gload16(bS[1] + k0, &Bs[buf][4096 + dstoff]);                 \
    }

    DN_STAGE(0, 0);
    DN_STAGE(1, 1);
    asm volatile("s_waitcnt vmcnt(3)" ::: "memory");
    __builtin_amdgcn_s_barrier();

    for (int t = 0; t < nk; ++t) {
        const bf16* Ab = As[t & 1];
        const bf16* Bb = Bs[t & 1];
        s16x8 a[4], b[4];
#pragma unroll
        for (int mi = 0; mi < 4; ++mi) a[mi] = *reinterpret_cast<const s16x8*>(Ab + offA[mi]);
#pragma unroll
        for (int ni = 0; ni < 4; ++ni) b[ni] = *reinterpret_cast<const s16x8*>(Bb + offB[ni]);
        __builtin_amdgcn_s_setprio(1);
#pragma unroll
        for (int mi = 0; mi < 4; ++mi)
#pragma unroll
            for (int ni = 0; ni < 4; ++ni)
                acc[mi][ni] = __builtin_amdgcn_mfma_f32_16x16x32_bf16(a[mi], b[ni], acc[mi][ni], 0, 0, 0);
        __builtin_amdgcn_s_setprio(0);
        __builtin_amdgcn_sched_barrier(0);
        __builtin_amdgcn_s_barrier();
        if (t + 2 < nk) DN_STAGE(t + 2, t & 1);
        if (t + 1 < nk) {
            if (t + 2 < nk) asm volatile("s_waitcnt vmcnt(3)" ::: "memory");
            else            asm volatile("s_waitcnt vmcnt(0)" ::: "memory");
            __builtin_amdgcn_s_barrier();
        }
    }
#undef DN_STAGE

    // epilogue: y[tok][col] += w * acc  (2 adds per element, commutative -> deterministic)
    int rbase = (lane >> 4) * 4, cbase = lane & 15;
#pragma unroll
    for (int mi = 0; mi < 4; ++mi) {
#pragma unroll
        for (int r = 0; r < 4; ++r) {
            int row = m0 + wrow + mi * 16 + rbase + r;
            if (row < ne) {
                int slot = base + row;
                int tok = list[slot];
                float w = slot_w[slot];
                float* yrow = y + (size_t)tok * DDIM + n0 + wcol + cbase;
#pragma unroll
                for (int ni = 0; ni < 4; ++ni)
                    atomicAdd(yrow + ni * 16, w * acc[mi][ni][r]);
            }
        }
    }
}

extern "C" void kernel_launch(void* const* d_in, const int* in_sizes, int n_in,
                              void* d_out, int out_size, void* d_ws, size_t ws_size,
                              hipStream_t stream) {
    const float* x  = (const float*)d_in[0];
    const float* rw = (const float*)d_in[1];
    const float* wg = (const float*)d_in[2];
    const float* wu = (const float*)d_in[3];
    const float* wd = (const float*)d_in[4];
    float* y = (float*)d_out;

    char* ws = (char*)d_ws;
    int*   r_e    = (int*)  (ws + 0);           // 2T ints
    float* r_w    = (float*)(ws + 32768);       // 2T floats
    int*   offs   = (int*)  (ws + 65600);       // 9
    int*   list   = (int*)  (ws + 65664);       // 2T ints
    float* slot_w = (float*)(ws + 98432);       // 2T floats
    bf16*  xb     = (bf16*) (ws + 1048576ull);      // 8 MB
    bf16*  wguT   = (bf16*) (ws + 16777216ull);     // 64 MB  [E][2H][D] interleaved g/u
    bf16*  wdT    = (bf16*) (ws + 83886080ull);     // 32 MB  [E][D][H]
    bf16*  hbuf   = (bf16*) (ws + 117440512ull);    // 32 MB  [slot][H]

    // weight transposes + casts (wg/wu interleaved into wguT rows 2h / 2h+1)
    transpose_cast_kernel<<<dim3(DDIM / 64, HDIM / 64, NEXP), 256, 0, stream>>>(
        wg, wguT, DDIM, HDIM, 2, 0, (size_t)2 * HDIM * DDIM);
    transpose_cast_kernel<<<dim3(DDIM / 64, HDIM / 64, NEXP), 256, 0, stream>>>(
        wu, wguT, DDIM, HDIM, 2, 1, (size_t)2 * HDIM * DDIM);
    transpose_cast_kernel<<<dim3(HDIM / 64, DDIM / 64, NEXP), 256, 0, stream>>>(
        wd, wdT, HDIM, DDIM, 1, 0, (size_t)DDIM * HDIM);

    // routing (+ fused x cast) and binning
    router_cast_kernel<<<dim3(T_TOK / 4), 256, 0, stream>>>(x, rw, r_e, r_w, xb);
    binning_kernel<<<dim3(1), 512, 0, stream>>>(r_e, r_w, offs, list, slot_w);

    // zero y (down accumulates into it atomically)
    hipMemsetAsync(d_out, 0, (size_t)out_size * sizeof(float), stream);

    // expert GEMMs (grouped, worst-case grid with early-exit)
    gateup_kernel<<<dim3(2 * HDIM / 256, T_TOK / 256, NEXP), 512, 0, stream>>>(xb, wguT, offs, list, hbuf);
    down_kernel<<<dim3(DDIM / 256, T_TOK / 128, NEXP), 512, 0, stream>>>(hbuf, wdT, offs, list, slot_w, y);
}

// Round 8
// 296.802 us; speedup vs baseline: 4.0288x; 4.0288x over previous
//
#include <hip/hip_runtime.h>
#include <hip/hip_bf16.h>

#define T_TOK 4096
#define DDIM  1024
#define HDIM  2048
#define NEXP  8

typedef __attribute__((ext_vector_type(4))) float f32x4;
typedef __attribute__((ext_vector_type(8))) short s16x8;
typedef __hip_bfloat16 bf16;

typedef const void __attribute__((address_space(1))) gvoid;
typedef void __attribute__((address_space(3))) svoid;

__device__ __forceinline__ void gload16(const void* g, void* l) {
    // async global->LDS, 16B/lane; LDS dest = wave-uniform base, HW adds lane*16
    __builtin_amdgcn_global_load_lds((gvoid*)g, (svoid*)l, 16, 0, 0);
}

// ---------------- router (fp64 acc, top-2 softmax) + fused x->bf16 cast ----------------
__global__ void router_cast_kernel(const float* __restrict__ x, const float* __restrict__ rw,
                                   int* __restrict__ r_e, float* __restrict__ r_w,
                                   bf16* __restrict__ xb) {
    int wave = threadIdx.x >> 6, lane = threadIdx.x & 63;
    int t = blockIdx.x * 4 + wave;
    const float* xr = x + (size_t)t * DDIM;
    bf16* xbr = xb + (size_t)t * DDIM;
    double acc[NEXP];
#pragma unroll
    for (int e = 0; e < NEXP; ++e) acc[e] = 0.0;
#pragma unroll
    for (int c = 0; c < 4; ++c) {
        int d = c * 256 + lane * 4;
        float4 v = *reinterpret_cast<const float4*>(xr + d);
        union { ushort4 u; bf16 h[4]; } o;
        o.h[0] = __float2bfloat16(v.x);
        o.h[1] = __float2bfloat16(v.y);
        o.h[2] = __float2bfloat16(v.z);
        o.h[3] = __float2bfloat16(v.w);
        *reinterpret_cast<ushort4*>(xbr + d) = o.u;
        const float* rw0 = rw + (size_t)d * NEXP;
#pragma unroll
        for (int j = 0; j < 4; ++j) {
            float xv = (&v.x)[j];
            const float* rwr = rw0 + j * NEXP;
#pragma unroll
            for (int e = 0; e < NEXP; ++e) acc[e] += (double)xv * (double)rwr[e];
        }
    }
#pragma unroll
    for (int e = 0; e < NEXP; ++e) {
#pragma unroll
        for (int off = 32; off > 0; off >>= 1) acc[e] += __shfl_down(acc[e], off);
    }
    if (lane == 0) {
        int i0 = 0; double v0 = acc[0];
#pragma unroll
        for (int e = 1; e < NEXP; ++e) if (acc[e] > v0) { v0 = acc[e]; i0 = e; }
        int i1 = -1; double v1 = -1e300;
#pragma unroll
        for (int e = 0; e < NEXP; ++e) { if (e == i0) continue; if (acc[e] > v1) { v1 = acc[e]; i1 = e; } }
        float w0 = 1.0f / (1.0f + expf((float)(v1 - v0)));
        float w1 = 1.0f - w0;
        r_e[2*t]   = i0; r_e[2*t+1] = i1;
        r_w[2*t]   = w0; r_w[2*t+1] = w1;
    }
}

// ---------------- fused binning: count + scan + fill in one block ----------------
__global__ void binning_kernel(const int* __restrict__ r_e, const float* __restrict__ r_w,
                               int* __restrict__ offs, int* __restrict__ list,
                               float* __restrict__ slot_w) {
    __shared__ int scnt[NEXP], scur[NEXP], soff[NEXP + 1];
    int tid = threadIdx.x;
    if (tid < NEXP) { scnt[tid] = 0; scur[tid] = 0; }
    __syncthreads();
    for (int i = tid; i < 2 * T_TOK; i += 512) atomicAdd(&scnt[r_e[i]], 1);
    __syncthreads();
    if (tid == 0) {
        int s = 0;
        for (int e = 0; e < NEXP; ++e) { soff[e] = s; s += scnt[e]; }
        soff[NEXP] = s;
    }
    __syncthreads();
    if (tid < NEXP + 1) offs[tid] = soff[tid];
    for (int i = tid; i < 2 * T_TOK; i += 512) {
        int e = r_e[i];
        int pos = atomicAdd(&scur[e], 1);
        int slot = soff[e] + pos;
        list[slot] = i >> 1;
        slot_w[slot] = r_w[i];
    }
}

// ---------------- transpose + fp32->bf16 cast (vectorized, generalized) ----------------
__global__ void transpose_cast_kernel(const float* __restrict__ in, bf16* __restrict__ out,
                                      int R, int C, int rmul, int roff, size_t outE) {
    __shared__ bf16 tile[64][68];
    const float* inp = in + (size_t)blockIdx.z * R * C;
    bf16* outp = out + (size_t)blockIdx.z * outE;
    int r0 = blockIdx.x * 64, c0 = blockIdx.y * 64;
    int tid = threadIdx.x;
#pragma unroll
    for (int i = 0; i < 4; ++i) {
        int idx = i * 256 + tid;
        int r = idx >> 4, c4 = (idx & 15) * 4;
        float4 v = *reinterpret_cast<const float4*>(inp + (size_t)(r0 + r) * C + c0 + c4);
        tile[r][c4 + 0] = __float2bfloat16(v.x);
        tile[r][c4 + 1] = __float2bfloat16(v.y);
        tile[r][c4 + 2] = __float2bfloat16(v.z);
        tile[r][c4 + 3] = __float2bfloat16(v.w);
    }
    __syncthreads();
#pragma unroll
    for (int i = 0; i < 4; ++i) {
        int idx = i * 256 + tid;
        int c = idx >> 4, r4 = (idx & 15) * 4;
        union { ushort4 u; bf16 h[4]; } w;
        w.h[0] = tile[r4 + 0][c];
        w.h[1] = tile[r4 + 1][c];
        w.h[2] = tile[r4 + 2][c];
        w.h[3] = tile[r4 + 3][c];
        *reinterpret_cast<ushort4*>(outp + ((size_t)(c0 + c) * rmul + roff) * R + r0 + r4) = w.u;
    }
}

// ======== pass 1: gate+up as ONE GEMM over interleaved wguT [2H][D] ========
// m97-faithful geometry: 128x128 tile, BK=64, 256 thr = 4 waves (2M x 2N),
// wave-out 64x64 (acc[4][4]) -> 0.5 ds_read_b128 per MFMA. Double-buffered
// 64KB LDS, counted vmcnt(8) (never drained mid-loop), 0-conflict XOR swizzle.
__global__ __launch_bounds__(256, 2)
void gateup_kernel(const bf16* __restrict__ xb, const bf16* __restrict__ wguT,
                   const int* __restrict__ offs, const int* __restrict__ list,
                   bf16* __restrict__ hbuf) {
    int e = blockIdx.z;
    int base = offs[e];
    int ne = offs[e + 1] - base;
    int m0 = blockIdx.y * 128;
    if (m0 >= ne) return;
    int n0 = blockIdx.x * 128;   // in 2H=4096 interleaved space

    __shared__ bf16 As[2][8192];   // 128 rows x 64 k, swizzled chunks (16KB/buf)
    __shared__ bf16 Bs[2][8192];

    int tid = threadIdx.x, lane = tid & 63, wid = tid >> 6;
    int sub = tid >> 3;                    // 0..31: row within 32-row issue group
    int koff = 8 * ((tid & 7) ^ (sub & 7)); // inverse-swizzled source chunk

    const bf16* bbase = wguT + (size_t)e * (2 * HDIM) * DDIM + (size_t)n0 * DDIM;

    // per-thread global sources: 4 A-row issues (gathered, clamped) + 4 B-row issues
    const bf16* aS[4]; const bf16* bS[4];
    int dst[4];
#pragma unroll
    for (int i = 0; i < 4; ++i) {
        int row = i * 32 + sub;
        int r = m0 + row; if (r > ne - 1) r = ne - 1;   // clamp: read-only, never stored
        aS[i] = xb + (size_t)list[base + r] * DDIM + koff;
        bS[i] = bbase + (size_t)row * DDIM + koff;
        dst[i] = (i * 32 + wid * 8) * 64;               // wave-uniform LDS elem offset
    }

    int rl = lane & 15, kq = 8 * (lane >> 4);
    int wrow = (wid >> 1) * 64;      // 2 M waves
    int wcol = (wid & 1) * 64;       // 2 N waves
    int xorv = (rl & 7) * 8;         // read-side swizzle (row&7 == rl&7 here)

    f32x4 zero4 = {0.f, 0.f, 0.f, 0.f};
    f32x4 acc[4][4];
#pragma unroll
    for (int mi = 0; mi < 4; ++mi)
#pragma unroll
        for (int ni = 0; ni < 4; ++ni) acc[mi][ni] = zero4;

    const int nk = DDIM / 64;   // 16

#define GU_STAGE(tt, buf)                                     \
    {                                                         \
        int k0 = (tt) * 64;                                   \
        _Pragma("unroll")                                     \
        for (int i = 0; i < 4; ++i) {                         \
            gload16(aS[i] + k0, &As[buf][dst[i]]);            \
            gload16(bS[i] + k0, &Bs[buf][dst[i]]);            \
        }                                                     \
    }

    // prologue: stage tiles 0,1 (8 loads each); wait tile0, keep tile1 in flight
    GU_STAGE(0, 0);
    GU_STAGE(1, 1);
    asm volatile("s_waitcnt vmcnt(8)" ::: "memory");
    __builtin_amdgcn_s_barrier();

    for (int t = 0; t < nk; ++t) {
        const bf16* Ab = As[t & 1];
        const bf16* Bb = Bs[t & 1];
#pragma unroll
        for (int kk = 0; kk < 2; ++kk) {
            int kos = (kk * 32 + kq) ^ xorv;
            s16x8 a[4], b[4];
#pragma unroll
            for (int mi = 0; mi < 4; ++mi)
                a[mi] = *reinterpret_cast<const s16x8*>(Ab + (wrow + mi * 16 + rl) * 64 + kos);
#pragma unroll
            for (int ni = 0; ni < 4; ++ni)
                b[ni] = *reinterpret_cast<const s16x8*>(Bb + (wcol + ni * 16 + rl) * 64 + kos);
            __builtin_amdgcn_s_setprio(1);
#pragma unroll
            for (int mi = 0; mi < 4; ++mi)
#pragma unroll
                for (int ni = 0; ni < 4; ++ni)
                    acc[mi][ni] = __builtin_amdgcn_mfma_f32_16x16x32_bf16(a[mi], b[ni], acc[mi][ni], 0, 0, 0);
            __builtin_amdgcn_s_setprio(0);
        }
        __builtin_amdgcn_sched_barrier(0);
        __builtin_amdgcn_s_barrier();                 // buf[t&1] free
        if (t + 2 < nk) GU_STAGE(t + 2, t & 1);       // in flight: t+1(8) + t+2(8)
        if (t + 1 < nk) {
            if (t + 2 < nk) asm volatile("s_waitcnt vmcnt(8)" ::: "memory");
            else            asm volatile("s_waitcnt vmcnt(0)" ::: "memory");
            __builtin_amdgcn_s_barrier();             // tile t+1 fully in LDS
        }
    }
#undef GU_STAGE

    // epilogue: even col = gate, odd col = up; pair via shfl_xor(1), even lanes store.
    int rbase = (lane >> 4) * 4, cbase = lane & 15;
    bool evenlane = (lane & 1) == 0;
#pragma unroll
    for (int mi = 0; mi < 4; ++mi) {
#pragma unroll
        for (int ni = 0; ni < 4; ++ni) {
#pragma unroll
            for (int r = 0; r < 4; ++r) {
                float own = acc[mi][ni][r];
                float oth = __shfl_xor(own, 1);
                int row = m0 + wrow + mi * 16 + rbase + r;
                if (evenlane && row < ne) {
                    float g = own, u = oth;
                    float h = (g / (1.0f + expf(-g))) * u;
                    int hcol = (n0 + wcol + ni * 16 + cbase) >> 1;
                    hbuf[(size_t)(base + row) * HDIM + hcol] = __float2bfloat16(h);
                }
            }
        }
    }
}

// ======== pass 2: down GEMM 128x128, same m97 geometry, fused atomic combine ========
// y zeroed first; each element gets exactly 2 commutative fp32 adds -> deterministic.
__global__ __launch_bounds__(256, 2)
void down_kernel(const bf16* __restrict__ hbuf, const bf16* __restrict__ wdT,
                 const int* __restrict__ offs, const int* __restrict__ list,
                 const float* __restrict__ slot_w, float* __restrict__ y) {
    int e = blockIdx.z;
    int base = offs[e];
    int ne = offs[e + 1] - base;
    int m0 = blockIdx.y * 128;
    if (m0 >= ne) return;
    int n0 = blockIdx.x * 128;   // d-tile

    __shared__ bf16 As[2][8192];
    __shared__ bf16 Bs[2][8192];

    int tid = threadIdx.x, lane = tid & 63, wid = tid >> 6;
    int sub = tid >> 3;
    int koff = 8 * ((tid & 7) ^ (sub & 7));

    const bf16* bbase = wdT + (size_t)e * DDIM * HDIM + (size_t)n0 * HDIM;

    const bf16* aS[4]; const bf16* bS[4];
    int dst[4];
#pragma unroll
    for (int i = 0; i < 4; ++i) {
        int row = i * 32 + sub;
        int r = m0 + row; if (r > ne - 1) r = ne - 1;
        aS[i] = hbuf + (size_t)(base + r) * HDIM + koff;
        bS[i] = bbase + (size_t)row * HDIM + koff;
        dst[i] = (i * 32 + wid * 8) * 64;
    }

    int rl = lane & 15, kq = 8 * (lane >> 4);
    int wrow = (wid >> 1) * 64;
    int wcol = (wid & 1) * 64;
    int xorv = (rl & 7) * 8;

    f32x4 zero4 = {0.f, 0.f, 0.f, 0.f};
    f32x4 acc[4][4];
#pragma unroll
    for (int mi = 0; mi < 4; ++mi)
#pragma unroll
        for (int ni = 0; ni < 4; ++ni) acc[mi][ni] = zero4;

    const int nk = HDIM / 64;   // 32

#define DN_STAGE(tt, buf)                                     \
    {                                                         \
        int k0 = (tt) * 64;                                   \
        _Pragma("unroll")                                     \
        for (int i = 0; i < 4; ++i) {                         \
            gload16(aS[i] + k0, &As[buf][dst[i]]);            \
            gload16(bS[i] + k0, &Bs[buf][dst[i]]);            \
        }                                                     \
    }

    DN_STAGE(0, 0);
    DN_STAGE(1, 1);
    asm volatile("s_waitcnt vmcnt(8)" ::: "memory");
    __builtin_amdgcn_s_barrier();

    for (int t = 0; t < nk; ++t) {
        const bf16* Ab = As[t & 1];
        const bf16* Bb = Bs[t & 1];
#pragma unroll
        for (int kk = 0; kk < 2; ++kk) {
            int kos = (kk * 32 + kq) ^ xorv;
            s16x8 a[4], b[4];
#pragma unroll
            for (int mi = 0; mi < 4; ++mi)
                a[mi] = *reinterpret_cast<const s16x8*>(Ab + (wrow + mi * 16 + rl) * 64 + kos);
#pragma unroll
            for (int ni = 0; ni < 4; ++ni)
                b[ni] = *reinterpret_cast<const s16x8*>(Bb + (wcol + ni * 16 + rl) * 64 + kos);
            __builtin_amdgcn_s_setprio(1);
#pragma unroll
            for (int mi = 0; mi < 4; ++mi)
#pragma unroll
                for (int ni = 0; ni < 4; ++ni)
                    acc[mi][ni] = __builtin_amdgcn_mfma_f32_16x16x32_bf16(a[mi], b[ni], acc[mi][ni], 0, 0, 0);
            __builtin_amdgcn_s_setprio(0);
        }
        __builtin_amdgcn_sched_barrier(0);
        __builtin_amdgcn_s_barrier();
        if (t + 2 < nk) DN_STAGE(t + 2, t & 1);
        if (t + 1 < nk) {
            if (t + 2 < nk) asm volatile("s_waitcnt vmcnt(8)" ::: "memory");
            else            asm volatile("s_waitcnt vmcnt(0)" ::: "memory");
            __builtin_amdgcn_s_barrier();
        }
    }
#undef DN_STAGE

    // epilogue: y[tok][col] += w * acc  (2 adds per element, commutative -> deterministic)
    int rbase = (lane >> 4) * 4, cbase = lane & 15;
#pragma unroll
    for (int mi = 0; mi < 4; ++mi) {
#pragma unroll
        for (int r = 0; r < 4; ++r) {
            int row = m0 + wrow + mi * 16 + rbase + r;
            if (row < ne) {
                int slot = base + row;
                int tok = list[slot];
                float w = slot_w[slot];
                float* yrow = y + (size_t)tok * DDIM + n0 + wcol + cbase;
#pragma unroll
                for (int ni = 0; ni < 4; ++ni)
                    atomicAdd(yrow + ni * 16, w * acc[mi][ni][r]);
            }
        }
    }
}

extern "C" void kernel_launch(void* const* d_in, const int* in_sizes, int n_in,
                              void* d_out, int out_size, void* d_ws, size_t ws_size,
                              hipStream_t stream) {
    const float* x  = (const float*)d_in[0];
    const float* rw = (const float*)d_in[1];
    const float* wg = (const float*)d_in[2];
    const float* wu = (const float*)d_in[3];
    const float* wd = (const float*)d_in[4];
    float* y = (float*)d_out;

    char* ws = (char*)d_ws;
    int*   r_e    = (int*)  (ws + 0);           // 2T ints
    float* r_w    = (float*)(ws + 32768);       // 2T floats
    int*   offs   = (int*)  (ws + 65600);       // 9
    int*   list   = (int*)  (ws + 65664);       // 2T ints
    float* slot_w = (float*)(ws + 98432);       // 2T floats
    bf16*  xb     = (bf16*) (ws + 1048576ull);      // 8 MB
    bf16*  wguT   = (bf16*) (ws + 16777216ull);     // 64 MB  [E][2H][D] interleaved g/u
    bf16*  wdT    = (bf16*) (ws + 83886080ull);     // 32 MB  [E][D][H]
    bf16*  hbuf   = (bf16*) (ws + 117440512ull);    // 32 MB  [slot][H]

    // weight transposes + casts (wg/wu interleaved into wguT rows 2h / 2h+1)
    transpose_cast_kernel<<<dim3(DDIM / 64, HDIM / 64, NEXP), 256, 0, stream>>>(
        wg, wguT, DDIM, HDIM, 2, 0, (size_t)2 * HDIM * DDIM);
    transpose_cast_kernel<<<dim3(DDIM / 64, HDIM / 64, NEXP), 256, 0, stream>>>(
        wu, wguT, DDIM, HDIM, 2, 1, (size_t)2 * HDIM * DDIM);
    transpose_cast_kernel<<<dim3(HDIM / 64, DDIM / 64, NEXP), 256, 0, stream>>>(
        wd, wdT, HDIM, DDIM, 1, 0, (size_t)DDIM * HDIM);

    // routing (+ fused x cast) and binning
    router_cast_kernel<<<dim3(T_TOK / 4), 256, 0, stream>>>(x, rw, r_e, r_w, xb);
    binning_kernel<<<dim3(1), 512, 0, stream>>>(r_e, r_w, offs, list, slot_w);

    // zero y (down accumulates into it atomically)
    hipMemsetAsync(d_out, 0, (size_t)out_size * sizeof(float), stream);

    // expert GEMMs (grouped, worst-case grid with early-exit)
    gateup_kernel<<<dim3(2 * HDIM / 128, T_TOK / 128, NEXP), 256, 0, stream>>>(xb, wguT, offs, list, hbuf);
    down_kernel<<<dim3(DDIM / 128, T_TOK / 128, NEXP), 256, 0, stream>>>(hbuf, wdT, offs, list, slot_w, y);
}